// Round 10
// baseline (191.937 us; speedup 1.0000x reference)
//
#include <hip/hip_runtime.h>

#define MM 4096
#define NN 4096
#define KK 4096
#define BM 256
#define BN 256
#define BK 32
#define NT (KK / BK)

typedef short          s16x8 __attribute__((ext_vector_type(8)));
typedef float          f32x4 __attribute__((ext_vector_type(4)));
typedef unsigned short us4   __attribute__((ext_vector_type(4)));
typedef unsigned short us8   __attribute__((ext_vector_type(8)));

#define MFMA16(a, b, c) __builtin_amdgcn_mfma_f32_16x16x32_bf16((a), (b), (c), 0, 0, 0)
#define SB0() __builtin_amdgcn_sched_barrier(0)
#define LGKM(n) asm volatile("s_waitcnt lgkmcnt(" #n ")" ::: "memory")
#define VMC(n)  asm volatile("s_waitcnt vmcnt(" #n ")" ::: "memory")

// ---------- helpers ----------

__device__ __forceinline__ unsigned short f2bf(float f) {
  unsigned int u = __float_as_uint(f);
  u += 0x7fffu + ((u >> 16) & 1u);
  return (unsigned short)(u >> 16);
}

__device__ __forceinline__ void gload16(const void* g, void* l) {
  __builtin_amdgcn_global_load_lds(
      (const __attribute__((address_space(1))) void*)g,
      (__attribute__((address_space(3))) void*)l, 16, 0, 0);
}

// ---------- kernel 1: 2:4 mask + binarize + cvt -> bf16 W_h (M x K) ----------

__global__ __launch_bounds__(256) void kquant(const float* __restrict__ w,
                                              unsigned short* __restrict__ wh) {
  int idx = blockIdx.x * 256 + threadIdx.x;
  const float4* p = (const float4*)w;
  float4 g0 = p[(size_t)idx * 2];
  float4 g1 = p[(size_t)idx * 2 + 1];
  float v[8] = {g0.x, g0.y, g0.z, g0.w, g1.x, g1.y, g1.z, g1.w};
  us8 o;
#pragma unroll
  for (int g = 0; g < 2; g++) {
    float av[4];
#pragma unroll
    for (int j = 0; j < 4; j++) av[j] = fabsf(v[g * 4 + j]);
#pragma unroll
    for (int j = 0; j < 4; j++) {
      int rank = 0;
#pragma unroll
      for (int k = 0; k < 4; k++) {
        if (k == j) continue;
        rank += (av[k] > av[j] || (av[k] == av[j] && k < j)) ? 1 : 0;
      }
      o[g * 4 + j] = (rank < 2 && v[g * 4 + j] > 0.0f) ? (unsigned short)0x3F80
                                                       : (unsigned short)0;
    }
  }
  *(us8*)(wh + (size_t)idx * 8) = o;
}

// ---------- kernel 2: x (K x N f32) -> xT (N x K bf16) ----------

__global__ __launch_bounds__(256) void ktranspose(const float* __restrict__ x,
                                                  unsigned short* __restrict__ xt) {
  __shared__ float tile[64][65];
  int bn = blockIdx.x;
  int bk = blockIdx.y;
  int t = threadIdx.x;
  int tc = (t & 15) << 2;
  int tr = t >> 4;
  const float* src = x + (size_t)(bk * 64 + tr) * NN + bn * 64 + tc;
#pragma unroll
  for (int i = 0; i < 4; i++) {
    float4 v = *(const float4*)(src + (size_t)i * 16 * NN);
    int r = tr + i * 16;
    tile[r][tc + 0] = v.x; tile[r][tc + 1] = v.y;
    tile[r][tc + 2] = v.z; tile[r][tc + 3] = v.w;
  }
  __syncthreads();
  unsigned short* dst = xt + (size_t)(bn * 64 + tr) * KK + bk * 64 + tc;
#pragma unroll
  for (int i = 0; i < 4; i++) {
    int n = tr + i * 16;
    us4 o;
    o.x = f2bf(tile[tc + 0][n]);
    o.y = f2bf(tile[tc + 1][n]);
    o.z = f2bf(tile[tc + 2][n]);
    o.w = f2bf(tile[tc + 3][n]);
    *(us4*)(dst + (size_t)i * 16 * KK) = o;
  }
}

// ---------- kernel 3: 256x256 GEMM, 4 fat waves (128x128/wave), BK=32 ------
// Per wave per tile: 16 ds_reads + 64 MFMA (vs 24+64 at 8 waves) -> per-CU
// LDS time (~1024 cyc incl. stage writes) < MFMA time (1242 cyc). 1 wave/SIMD
// (acc 256 AGPR + dual frag sets): hiding is pure ILP — mid-tile VMC(0)+
// barrier certifies next buffer, next-tile frag reads issue between the MFMA
// half-clusters, one LGKM(0) gate at tile end. Swizzle/staging = round-9's
// measured-0-conflict 64B-row pattern.

__global__ __launch_bounds__(256, 1) void kgemm(const unsigned short* __restrict__ A,
                                                const unsigned short* __restrict__ B,
                                                float* __restrict__ C) {
  __shared__ __align__(16) unsigned short lds[32768];  // A0|A1|B0|B1, 64 KiB

  const int tid  = threadIdx.x;
  // XCD swizzle: bijective over the 16x16 block grid (4x8 rect per XCD).
  const int bid  = blockIdx.x;
  const int xcd  = bid & 7;
  const int j    = bid >> 3;                  // 0..31
  const int bmi  = (xcd >> 1) * 4 + (j >> 3); // 0..15
  const int bni  = (xcd & 1) * 8 + (j & 7);   // 0..15
  const int lane = tid & 63;
  const int wave = tid >> 6;
  const int wm   = wave >> 1;   // 0..1
  const int wn   = wave & 1;    // 0..1
  const int llo  = lane & 15;
  const int lhi  = lane >> 4;   // 0..3

  // staging (linear LDS dest; inverse-swizzled global source), 64B rows
  const int srow  = tid >> 2;                      // 0..63 per 64-row chunk
  const int sgran = (tid & 3) ^ ((tid >> 3) & 3);  // g ^ ((row>>1)&3)
  const unsigned short* ga = A + (size_t)(bmi * BM + srow) * KK + sgran * 8;
  const unsigned short* gb = B + (size_t)(bni * BN + srow) * KK + sgran * 8;

  // fragment read offsets (swizzled, measured 0-conflict in round 9)
  const int ok   = ((lhi ^ ((llo >> 1) & 3)) << 3);
  const int arow = (wm * 128 + llo) * BK;
  const int brow = (wn * 128 + llo) * BK;

  f32x4 acc[8][8] = {};
  s16x8 afA[8], bfA[8], afB[8], bfB[8];

  auto stage = [&](int buf, int t) {   // 4 A-gloads + 4 B-gloads
    const unsigned short* pa = ga + (size_t)t * BK;
    const unsigned short* pb = gb + (size_t)t * BK;
    unsigned short* la = &lds[buf * 8192 + tid * 8];
    unsigned short* lb = &lds[16384 + buf * 8192 + tid * 8];
#pragma unroll
    for (int h = 0; h < 4; h++)
      gload16(pa + (size_t)h * 64 * KK, la + h * 2048);
#pragma unroll
    for (int h = 0; h < 4; h++)
      gload16(pb + (size_t)h * 64 * KK, lb + h * 2048);
  };

  auto tile = [&](int cur, s16x8 (&afC)[8], s16x8 (&bfC)[8],
                  s16x8 (&afN)[8], s16x8 (&bfN)[8], int t) {
    const unsigned short* sa_n = &lds[(cur ^ 1) * 8192];
    const unsigned short* sb_n = &lds[16384 + (cur ^ 1) * 8192];

    // stage t+1 -> buf^1 (readers of buf^1 retired end-of-(t-2), sep. by barrier)
    stage(cur ^ 1, (t + 1) & (NT - 1));
    SB0();

    // first half: afC x bfC[0..3] (32 MFMA) — covers stage flight
    __builtin_amdgcn_s_setprio(1);
#pragma unroll
    for (int m = 0; m < 8; m++)
#pragma unroll
      for (int n = 0; n < 4; n++)
        acc[m][n] = MFMA16(afC[m], bfC[n], acc[m][n]);
    __builtin_amdgcn_s_setprio(0);
    SB0();

    VMC(0); SB0();
    __builtin_amdgcn_s_barrier(); SB0();

    // next-tile A frags (8 reads) — drain under next 16 MFMA
#pragma unroll
    for (int m = 0; m < 8; m++)
      afN[m] = *(const s16x8*)(sa_n + arow + m * 512 + ok);
    SB0();

    __builtin_amdgcn_s_setprio(1);
#pragma unroll
    for (int m = 0; m < 8; m++)
#pragma unroll
      for (int n = 4; n < 6; n++)
        acc[m][n] = MFMA16(afC[m], bfC[n], acc[m][n]);
    __builtin_amdgcn_s_setprio(0);
    SB0();

    // next-tile B frags (8 reads) — drain under last 16 MFMA
#pragma unroll
    for (int n = 0; n < 8; n++)
      bfN[n] = *(const s16x8*)(sb_n + brow + n * 512 + ok);
    SB0();

    __builtin_amdgcn_s_setprio(1);
#pragma unroll
    for (int m = 0; m < 8; m++)
#pragma unroll
      for (int n = 6; n < 8; n++)
        acc[m][n] = MFMA16(afC[m], bfC[n], acc[m][n]);
    __builtin_amdgcn_s_setprio(0);
    SB0();

    LGKM(0); SB0();   // gate next-tile frags
  };

  // prologue: tile 0 -> buf0, certify, load set A, gate
  stage(0, 0);
  VMC(0); SB0();
  __builtin_amdgcn_s_barrier(); SB0();
#pragma unroll
  for (int m = 0; m < 8; m++)
    afA[m] = *(const s16x8*)(&lds[0] + arow + m * 512 + ok);
#pragma unroll
  for (int n = 0; n < 8; n++)
    bfA[n] = *(const s16x8*)(&lds[16384] + brow + n * 512 + ok);
  LGKM(0); SB0();

  for (int it = 0; it < NT / 2; ++it) {
    tile(0, afA, bfA, afB, bfB, 2 * it);
    tile(1, afB, bfB, afA, bfA, 2 * it + 1);
  }

  // ---- epilogue: D layout col = lane&15, row = (lane>>4)*4 + reg ----
  const int crow0 = bmi * BM + wm * 128 + lhi * 4;
  const int ccol0 = bni * BN + wn * 128 + llo;
#pragma unroll
  for (int m = 0; m < 8; m++)
#pragma unroll
    for (int n = 0; n < 8; n++) {
      float* cp = C + (size_t)(crow0 + m * 16) * NN + ccol0 + n * 16;
#pragma unroll
      for (int v = 0; v < 4; v++) cp[(size_t)v * NN] = acc[m][n][v];
    }
}

// ---------- fallback: fused fp32 tiled GEMM (workspace too small) ----------

__device__ __forceinline__ float binq_elem(const float g[4], int j) {
  float aj = fabsf(g[j]);
  int rank = 0;
#pragma unroll
  for (int k = 0; k < 4; k++) {
    if (k == j) continue;
    float ak = fabsf(g[k]);
    rank += (ak > aj || (ak == aj && k < j)) ? 1 : 0;
  }
  return (rank < 2 && g[j] > 0.0f) ? 1.0f : 0.0f;
}

__global__ __launch_bounds__(256) void kfallback(const float* __restrict__ x,
                                                 const float* __restrict__ w,
                                                 float* __restrict__ c) {
  __shared__ float sA[16][17];
  __shared__ float sB[16][17];
  int tx = threadIdx.x, ty = threadIdx.y;
  int row = blockIdx.y * 16 + ty;
  int col = blockIdx.x * 16 + tx;
  float acc = 0.0f;
  for (int k0 = 0; k0 < KK; k0 += 16) {
    int k = k0 + tx;
    const float* g = &w[(size_t)row * KK + (k & ~3)];
    float gv[4] = {g[0], g[1], g[2], g[3]};
    sA[ty][tx] = binq_elem(gv, k & 3);
    sB[ty][tx] = x[(size_t)(k0 + ty) * NN + col];
    __syncthreads();
#pragma unroll
    for (int kk = 0; kk < 16; kk++) acc += sA[ty][kk] * sB[kk][tx];
    __syncthreads();
  }
  c[(size_t)row * NN + col] = acc;
}

// ---------- launcher ----------

extern "C" void kernel_launch(void* const* d_in, const int* in_sizes, int n_in,
                              void* d_out, int out_size, void* d_ws, size_t ws_size,
                              hipStream_t stream) {
  const float* x = (const float*)d_in[0];
  const float* w = (const float*)d_in[1];
  float* out = (float*)d_out;

  const size_t need = (size_t)MM * KK * 2 + (size_t)NN * KK * 2;
  if (ws_size < need) {
    dim3 blk(16, 16);
    dim3 grd(NN / 16, MM / 16);
    kfallback<<<grd, blk, 0, stream>>>(x, w, out);
    return;
  }

  unsigned short* wh = (unsigned short*)d_ws;
  unsigned short* xt = wh + (size_t)MM * KK;

  kquant<<<(MM * (size_t)KK / 8) / 256, 256, 0, stream>>>(w, wh);
  ktranspose<<<dim3(NN / 64, KK / 64), 256, 0, stream>>>(x, xt);
  kgemm<<<dim3((MM / BM) * (NN / BN)), 256, 0, stream>>>(wh, xt, out);
}

// Round 11
// 129.904 us; speedup vs baseline: 1.4775x; 1.4775x over previous
//
#include <hip/hip_runtime.h>

#define MM 4096
#define NN 4096
#define KK 4096
#define BM 256
#define BN 256
#define BK 64
#define NT (KK / BK)

typedef short          s16x8 __attribute__((ext_vector_type(8)));
typedef float          f32x4 __attribute__((ext_vector_type(4)));
typedef unsigned short us4   __attribute__((ext_vector_type(4)));
typedef unsigned short us8   __attribute__((ext_vector_type(8)));

#define MFMA16(a, b, c) __builtin_amdgcn_mfma_f32_16x16x32_bf16((a), (b), (c), 0, 0, 0)
#define SB0() __builtin_amdgcn_sched_barrier(0)
#define LGKM(n) asm volatile("s_waitcnt lgkmcnt(" #n ")" ::: "memory")
#define VMC(n)  asm volatile("s_waitcnt vmcnt(" #n ")" ::: "memory")

// ---------- helpers ----------

__device__ __forceinline__ unsigned short f2bf(float f) {
  unsigned int u = __float_as_uint(f);
  u += 0x7fffu + ((u >> 16) & 1u);
  return (unsigned short)(u >> 16);
}

__device__ __forceinline__ void gload16(const void* g, void* l) {
  __builtin_amdgcn_global_load_lds(
      (const __attribute__((address_space(1))) void*)g,
      (__attribute__((address_space(3))) void*)l, 16, 0, 0);
}

// ---------- kernel 1: fused preprocessing ----------
// blocks [0, 8192):  2:4 mask + binarize + cvt -> W_h bf16 (M x K)
// blocks [8192, 12288): x (K x N f32) -> xT (N x K bf16), 64x64 LDS transpose

__global__ __launch_bounds__(256) void kpre(const float* __restrict__ w,
                                            const float* __restrict__ x,
                                            unsigned short* __restrict__ wh,
                                            unsigned short* __restrict__ xt) {
  __shared__ float tile[64][65];
  const int t = threadIdx.x;

  if (blockIdx.x < 8192) {
    // ---- quant path ----
    int idx = blockIdx.x * 256 + t;
    const float4* p = (const float4*)w;
    float4 g0 = p[(size_t)idx * 2];
    float4 g1 = p[(size_t)idx * 2 + 1];
    float v[8] = {g0.x, g0.y, g0.z, g0.w, g1.x, g1.y, g1.z, g1.w};
    us8 o;
#pragma unroll
    for (int g = 0; g < 2; g++) {
      float av[4];
#pragma unroll
      for (int j = 0; j < 4; j++) av[j] = fabsf(v[g * 4 + j]);
#pragma unroll
      for (int j = 0; j < 4; j++) {
        int rank = 0;
#pragma unroll
        for (int k = 0; k < 4; k++) {
          if (k == j) continue;
          rank += (av[k] > av[j] || (av[k] == av[j] && k < j)) ? 1 : 0;
        }
        o[g * 4 + j] = (rank < 2 && v[g * 4 + j] > 0.0f) ? (unsigned short)0x3F80
                                                         : (unsigned short)0;
      }
    }
    *(us8*)(wh + (size_t)idx * 8) = o;
    return;
  }

  // ---- transpose path ----
  int bid2 = blockIdx.x - 8192;
  int bn = bid2 & 63;
  int bk = bid2 >> 6;
  int tc = (t & 15) << 2;
  int tr = t >> 4;
  const float* src = x + (size_t)(bk * 64 + tr) * NN + bn * 64 + tc;
#pragma unroll
  for (int i = 0; i < 4; i++) {
    float4 v = *(const float4*)(src + (size_t)i * 16 * NN);
    int r = tr + i * 16;
    tile[r][tc + 0] = v.x; tile[r][tc + 1] = v.y;
    tile[r][tc + 2] = v.z; tile[r][tc + 3] = v.w;
  }
  __syncthreads();
  unsigned short* dst = xt + (size_t)(bn * 64 + tr) * KK + bk * 64 + tc;
#pragma unroll
  for (int i = 0; i < 4; i++) {
    int n = tr + i * 16;
    us4 o;
    o.x = f2bf(tile[tc + 0][n]);
    o.y = f2bf(tile[tc + 1][n]);
    o.z = f2bf(tile[tc + 2][n]);
    o.w = f2bf(tile[tc + 3][n]);
    *(us4*)(dst + (size_t)i * 16 * KK) = o;
  }
}

// ---------- kernel 2: 256x256 GEMM (round-8 champion + stage-hoist) --------
// 8 waves (2M x 4N), BK=64, dbuf LDS, 16x16x32 MFMA, 0-conflict swizzle.
// Quadrant order Q00(af*b0), Q10(af2*b0), Q01(af*b1), Q11(af2*b1); next-tile
// ds_reads issue into just-freed regs. CHANGE vs round-8: the 8 stage gloads
// issue BEFORE the top LGKM(12) gate (no dependence on ds_reads), so HBM
// flight starts ~300 cyc earlier and the mid-tile VMC(0) wait shrinks.

__global__ __launch_bounds__(512, 2) void kgemm(const unsigned short* __restrict__ A,
                                                const unsigned short* __restrict__ B,
                                                float* __restrict__ C) {
  __shared__ __align__(16) unsigned short lds[4 * BM * BK];  // A0|A1|B0|B1, 128 KiB

  const int tid  = threadIdx.x;
  // XCD swizzle: xcd = bid&7; each XCD owns a 4x8 rectangle of the 16x16 grid.
  const int bid  = blockIdx.x;
  const int xcd  = bid & 7;
  const int j    = bid >> 3;
  const int bmi  = (xcd >> 1) * 4 + (j >> 3);
  const int bni  = (xcd & 1) * 8 + (j & 7);
  const int lane = tid & 63;
  const int wave = tid >> 6;
  const int wm   = wave >> 2;
  const int wn   = wave & 3;
  const int llo  = lane & 15;
  const int lhi  = lane >> 4;

  // staging addresses (linear LDS dest; inverse-swizzled global source)
  const int srow  = tid >> 3;
  const int scol  = (tid & 7) << 3;
  const int scolz = scol ^ ((srow & 7) << 3);
  const unsigned short* ga = A + (size_t)(bmi * BM + srow) * KK + scolz;
  const unsigned short* gb = B + (size_t)(bni * BN + srow) * KK + scolz;

  // fragment read offsets (swizzled) — proven 0-conflict pattern
  const int swz  = (llo & 7) << 3;
  const int ok0  = (lhi * 8) ^ swz;
  const int ok1  = (32 + lhi * 8) ^ swz;
  const int arow = (wm * 128 + llo) * BK;
  const int brow = (wn * 64 + llo) * BK;

  f32x4 acc[8][4] = {};
  s16x8 af[4][2], af2[4][2], b0[2][2], b1[2][2];

  auto stageA = [&](int buf, int t, int h) {
    const unsigned short* p = ga + (size_t)t * BK;
    unsigned short* l = &lds[buf * 16384 + tid * 8];
#pragma unroll
    for (int jj = 0; jj < 2; jj++)
      gload16(p + (size_t)(2 * h + jj) * 64 * KK, l + (2 * h + jj) * 4096);
  };
  auto stageB = [&](int buf, int t, int h) {
    const unsigned short* p = gb + (size_t)t * BK;
    unsigned short* l = &lds[32768 + buf * 16384 + tid * 8];
#pragma unroll
    for (int jj = 0; jj < 2; jj++)
      gload16(p + (size_t)(2 * h + jj) * 64 * KK, l + (2 * h + jj) * 4096);
  };

  // read groups: issue order fixed by SB0 fences; in-order DS retirement
  auto readB0 = [&](const unsigned short* sb_) {   // 4 reads
#pragma unroll
    for (int n = 0; n < 2; n++) {
      b0[n][0] = *(const s16x8*)(sb_ + brow + n * 16 * BK + ok0);
      b0[n][1] = *(const s16x8*)(sb_ + brow + n * 16 * BK + ok1);
    }
  };
  auto readB1 = [&](const unsigned short* sb_) {   // 4 reads
#pragma unroll
    for (int n = 0; n < 2; n++) {
      b1[n][0] = *(const s16x8*)(sb_ + brow + (32 + n * 16) * BK + ok0);
      b1[n][1] = *(const s16x8*)(sb_ + brow + (32 + n * 16) * BK + ok1);
    }
  };
  auto readAF = [&](const unsigned short* sa_) {   // 8 reads
#pragma unroll
    for (int m = 0; m < 4; m++) {
      af[m][0] = *(const s16x8*)(sa_ + arow + m * 16 * BK + ok0);
      af[m][1] = *(const s16x8*)(sa_ + arow + m * 16 * BK + ok1);
    }
  };
  auto readAF2 = [&](const unsigned short* sa_) {  // 8 reads
#pragma unroll
    for (int m = 0; m < 4; m++) {
      af2[m][0] = *(const s16x8*)(sa_ + arow + (64 + m * 16) * BK + ok0);
      af2[m][1] = *(const s16x8*)(sa_ + arow + (64 + m * 16) * BK + ok1);
    }
  };

  // prologue: tile 0 -> buf0; certify; issue tile-0 reads in gate order
  stageA(0, 0, 0); stageA(0, 0, 1);
  stageB(0, 0, 0); stageB(0, 0, 1);
  VMC(0); SB0();
  __builtin_amdgcn_s_barrier(); SB0();
  readB0(&lds[32768]); readAF(&lds[0]); SB0();      // G1: 12
  readAF2(&lds[0]); readB1(&lds[32768]); SB0();     // G2: 12

  for (int t = 0; t < NT; ++t) {
    const int cur = t & 1;
    const unsigned short* sa_n = &lds[(cur ^ 1) * 16384];
    const unsigned short* sb_n = &lds[32768 + (cur ^ 1) * 16384];
    const int tn = (t + 1) & (NT - 1);   // wraps on last iter (dead loads/reads)

    // stage tile t+1 into buf^1 FIRST (no dep on ds_reads; readers of buf^1
    // retired by mid-tile t-1 gates + barrier)
    stageA(cur ^ 1, tn, 0); stageA(cur ^ 1, tn, 1);
    stageB(cur ^ 1, tn, 0); stageB(cur ^ 1, tn, 1);
    SB0();

    // gate G1 (b0+af of tile t)
    LGKM(12); SB0();

    // Q00: af x b0
    __builtin_amdgcn_s_setprio(1);
#pragma unroll
    for (int m = 0; m < 4; m++)
#pragma unroll
      for (int n = 0; n < 2; n++) {
        acc[m][n] = MFMA16(af[m][0], b0[n][0], acc[m][n]);
        acc[m][n] = MFMA16(af[m][1], b0[n][1], acc[m][n]);
      }
    __builtin_amdgcn_s_setprio(0);
    SB0();

    // gate af2 (first 8 of G2; <=4 leaves only b1 outstanding)
    LGKM(4); SB0();

    // Q10: af2 x b0  (b0 dead after this)
    __builtin_amdgcn_s_setprio(1);
#pragma unroll
    for (int m = 0; m < 4; m++)
#pragma unroll
      for (int n = 0; n < 2; n++) {
        acc[4 + m][n] = MFMA16(af2[m][0], b0[n][0], acc[4 + m][n]);
        acc[4 + m][n] = MFMA16(af2[m][1], b0[n][1], acc[4 + m][n]);
      }
    __builtin_amdgcn_s_setprio(0);
    SB0();

    // certify buf^1 (stage issued at tile top: Q00+Q10+gate cover)
    VMC(0); SB0();
    __builtin_amdgcn_s_barrier(); SB0();

    // read b0_next into freed b0 regs (drains under Q01)
    readB0(sb_n); SB0();

    // gate b1 (last 4 of old G2; <=4 leaves only b0_next outstanding)
    LGKM(4); SB0();

    // Q01: af x b1  (af dead after this)
    __builtin_amdgcn_s_setprio(1);
#pragma unroll
    for (int m = 0; m < 4; m++)
#pragma unroll
      for (int n = 0; n < 2; n++) {
        acc[m][2 + n] = MFMA16(af[m][0], b1[n][0], acc[m][2 + n]);
        acc[m][2 + n] = MFMA16(af[m][1], b1[n][1], acc[m][2 + n]);
      }
    __builtin_amdgcn_s_setprio(0);
    SB0();

    // read af_next into freed af regs (drains under Q11)
    readAF(sa_n); SB0();

    // Q11: af2 x b1  (af2, b1 dead after this)
    __builtin_amdgcn_s_setprio(1);
#pragma unroll
    for (int m = 0; m < 4; m++)
#pragma unroll
      for (int n = 0; n < 2; n++) {
        acc[4 + m][2 + n] = MFMA16(af2[m][0], b1[n][0], acc[4 + m][2 + n]);
        acc[4 + m][2 + n] = MFMA16(af2[m][1], b1[n][1], acc[4 + m][2 + n]);
      }
    __builtin_amdgcn_s_setprio(0);
    SB0();

    // read af2_next + b1_next (drain under next tile's Q00/Q10)
    readAF2(sa_n); readB1(sb_n); SB0();
  }

  // ---- epilogue: D layout col = lane&15, row = (lane>>4)*4 + reg ----
  const int crow0 = bmi * BM + wm * 128 + lhi * 4;
  const int ccol0 = bni * BN + wn * 64 + llo;
#pragma unroll
  for (int m = 0; m < 8; m++)
#pragma unroll
    for (int n = 0; n < 4; n++) {
      float* cp = C + (size_t)(crow0 + m * 16) * NN + ccol0 + n * 16;
#pragma unroll
      for (int v = 0; v < 4; v++) cp[(size_t)v * NN] = acc[m][n][v];
    }
}

// ---------- fallback: fused fp32 tiled GEMM (workspace too small) ----------

__device__ __forceinline__ float binq_elem(const float g[4], int j) {
  float aj = fabsf(g[j]);
  int rank = 0;
#pragma unroll
  for (int k = 0; k < 4; k++) {
    if (k == j) continue;
    float ak = fabsf(g[k]);
    rank += (ak > aj || (ak == aj && k < j)) ? 1 : 0;
  }
  return (rank < 2 && g[j] > 0.0f) ? 1.0f : 0.0f;
}

__global__ __launch_bounds__(256) void kfallback(const float* __restrict__ x,
                                                 const float* __restrict__ w,
                                                 float* __restrict__ c) {
  __shared__ float sA[16][17];
  __shared__ float sB[16][17];
  int tx = threadIdx.x, ty = threadIdx.y;
  int row = blockIdx.y * 16 + ty;
  int col = blockIdx.x * 16 + tx;
  float acc = 0.0f;
  for (int k0 = 0; k0 < KK; k0 += 16) {
    int k = k0 + tx;
    const float* g = &w[(size_t)row * KK + (k & ~3)];
    float gv[4] = {g[0], g[1], g[2], g[3]};
    sA[ty][tx] = binq_elem(gv, k & 3);
    sB[ty][tx] = x[(size_t)(k0 + ty) * NN + col];
    __syncthreads();
#pragma unroll
    for (int kk = 0; kk < 16; kk++) acc += sA[ty][kk] * sB[kk][tx];
    __syncthreads();
  }
  c[(size_t)row * NN + col] = acc;
}

// ---------- launcher ----------

extern "C" void kernel_launch(void* const* d_in, const int* in_sizes, int n_in,
                              void* d_out, int out_size, void* d_ws, size_t ws_size,
                              hipStream_t stream) {
  const float* x = (const float*)d_in[0];
  const float* w = (const float*)d_in[1];
  float* out = (float*)d_out;

  const size_t need = (size_t)MM * KK * 2 + (size_t)NN * KK * 2;
  if (ws_size < need) {
    dim3 blk(16, 16);
    dim3 grd(NN / 16, MM / 16);
    kfallback<<<grd, blk, 0, stream>>>(x, w, out);
    return;
  }

  unsigned short* wh = (unsigned short*)d_ws;
  unsigned short* xt = wh + (size_t)MM * KK;

  kpre<<<12288, 256, 0, stream>>>(w, x, wh, xt);
  kgemm<<<dim3((MM / BM) * (NN / BN)), 512, 0, stream>>>(wh, xt, out);
}